// Round 7
// baseline (785.361 us; speedup 1.0000x reference)
//
#include <hip/hip_runtime.h>
#include <stdint.h>

#define N_BOX 8192
#define NWORDS 128   // N_BOX / 64

// ---------------------------------------------------------------------------
// Kernel 1: stable descending sort by score via bitonic sort of uint64 keys.
// key = (score_bits << 32) | (0xFFFFFFFF - idx)  -> descending sort gives
// score desc, ties broken by original index ascending (matches stable
// jnp.argsort(-scores)). Scores are >= 0 so raw float bits are monotonic.
// Then gather sorted boxes + areas.
// ---------------------------------------------------------------------------
__global__ __launch_bounds__(1024) void sort_kernel(
    const float* __restrict__ boxes, const float* __restrict__ scores,
    uint32_t* __restrict__ order,
    float* __restrict__ sx1, float* __restrict__ sy1,
    float* __restrict__ sx2, float* __restrict__ sy2,
    float* __restrict__ sarea)
{
    extern __shared__ unsigned long long s[];
    const int tid = threadIdx.x;

    for (int i = tid; i < N_BOX; i += 1024) {
        uint32_t bits = __float_as_uint(scores[i]);
        s[i] = ((unsigned long long)bits << 32) |
               (unsigned long long)(0xFFFFFFFFu - (uint32_t)i);
    }
    __syncthreads();

    for (int k = 2; k <= N_BOX; k <<= 1) {
        for (int j = k >> 1; j > 0; j >>= 1) {
            for (int idx = tid; idx < N_BOX; idx += 1024) {
                int ixj = idx ^ j;
                if (ixj > idx) {
                    unsigned long long a = s[idx], b = s[ixj];
                    bool desc = ((idx & k) == 0);   // final pass: all descending
                    if (desc ? (a < b) : (a > b)) { s[idx] = b; s[ixj] = a; }
                }
            }
            __syncthreads();
        }
    }

    for (int i = tid; i < N_BOX; i += 1024) {
        unsigned long long key = s[i];
        uint32_t idx = 0xFFFFFFFFu - (uint32_t)(key & 0xFFFFFFFFull);
        order[i] = idx;
        float x1 = boxes[idx * 4 + 0], y1 = boxes[idx * 4 + 1];
        float x2 = boxes[idx * 4 + 2], y2 = boxes[idx * 4 + 3];
        sx1[i] = x1; sy1[i] = y1; sx2[i] = x2; sy2[i] = y2;
        sarea[i] = (x2 - x1 + 1.0f) * (y2 - y1 + 1.0f);
    }
}

// ---------------------------------------------------------------------------
// Kernel 2: suppression bitmask. Block = 64 threads = 64 rows; each block
// handles one (row_block, col_block) 64x64 tile, col_block >= row_block.
// Bit c of mask[i][cb] set iff iou(i, cb*64+c) > 0.5 and j > i.
// Float op order matches the reference exactly: (a_i + a_j) - inter, true
// division. An empty asm barrier pins the ROUNDED value of `inter` so
// -ffp-contract=fast (hipcc default) cannot fuse `ssum - w*h` into an fma,
// which would skip numpy's intermediate rounding and could flip iou>0.5
// at the boundary.
// ---------------------------------------------------------------------------
__global__ __launch_bounds__(64) void mask_kernel(
    const float* __restrict__ sx1, const float* __restrict__ sy1,
    const float* __restrict__ sx2, const float* __restrict__ sy2,
    const float* __restrict__ sarea,
    unsigned long long* __restrict__ mask)
{
    const int cb = blockIdx.x, rb = blockIdx.y;
    if (cb < rb) return;

    __shared__ float cx1[64], cy1[64], cx2[64], cy2[64], ca[64];
    const int l = threadIdx.x;
    const int j0 = cb * 64;
    cx1[l] = sx1[j0 + l]; cy1[l] = sy1[j0 + l];
    cx2[l] = sx2[j0 + l]; cy2[l] = sy2[j0 + l];
    ca[l]  = sarea[j0 + l];
    __syncthreads();

    const int i = rb * 64 + l;
    const float x1 = sx1[i], y1 = sy1[i], x2 = sx2[i], y2 = sy2[i];
    const float ai = sarea[i];

    unsigned long long m = 0ull;
    for (int c = 0; c < 64; ++c) {
        const int j = j0 + c;
        float xx1 = fmaxf(x1, cx1[c]);
        float yy1 = fmaxf(y1, cy1[c]);
        float xx2 = fminf(x2, cx2[c]);
        float yy2 = fminf(y2, cy2[c]);
        float w = fmaxf(xx2 - xx1 + 1.0f, 0.0f);
        float h = fmaxf(yy2 - yy1 + 1.0f, 0.0f);
        float inter = w * h;
        asm volatile("" : "+v"(inter));   // pin rounded mul; block fma contraction
        float ssum  = ai + ca[c];
        float denom = ssum - inter;
        float iou   = inter / denom;
        if ((iou > 0.5f) && (j > i)) m |= (1ull << c);
    }
    mask[(size_t)i * NWORDS + cb] = m;
}

// ---------------------------------------------------------------------------
// Kernel 3: sequential greedy suppression scan (single block, 1024 threads).
// remv[t] accumulates suppressed bits for 64-column block t.
// Per row-block b: wave 0 runs the serial 64-step inner scan (shfl
// broadcasts, fully unrolled -> dep chain is just test+or), then
// 8 row-lanes x 128 word-lanes OR kept rows' mask words into remv[t>b].
// ---------------------------------------------------------------------------
__global__ __launch_bounds__(1024) void scan_kernel(
    const unsigned long long* __restrict__ mask,
    unsigned long long* __restrict__ remv_out)
{
    __shared__ unsigned long long remv[NWORDS];
    __shared__ unsigned long long keptS;
    const int tid = threadIdx.x;
    if (tid < NWORDS) remv[tid] = 0ull;
    __syncthreads();

    for (int b = 0; b < NWORDS; ++b) {
        if (tid < 64) {
            unsigned long long m = mask[(size_t)(b * 64 + tid) * NWORDS + b];
            unsigned int mlo = (unsigned int)m;
            unsigned int mhi = (unsigned int)(m >> 32);
            unsigned long long rem = remv[b];
            #pragma unroll
            for (int i = 0; i < 64; ++i) {
                unsigned int blo = __shfl(mlo, i, 64);
                unsigned int bhi = __shfl(mhi, i, 64);
                unsigned long long mi =
                    ((unsigned long long)bhi << 32) | (unsigned long long)blo;
                if (!((rem >> i) & 1ull)) rem |= mi;
            }
            if (tid == 0) { remv[b] = rem; keptS = ~rem; }
        }
        __syncthreads();

        const unsigned long long kept = keptS;
        const int t = tid & 127;
        const int r = tid >> 7;
        if (t > b && kept) {
            unsigned long long acc = 0ull;
            for (int i = r; i < 64; i += 8) {
                if ((kept >> i) & 1ull)
                    acc |= mask[(size_t)(b * 64 + i) * NWORDS + t];
            }
            if (acc) atomicOr(&remv[t], acc);
        }
        __syncthreads();
    }

    if (tid < NWORDS) remv_out[tid] = remv[tid];
}

// ---------------------------------------------------------------------------
// Kernel 4: scatter keep mask back to original order as int32 0/1.
// The reference output dtype is bool -> harness reads d_out as int32.
// ---------------------------------------------------------------------------
__global__ __launch_bounds__(256) void output_kernel(
    const unsigned long long* __restrict__ remv,
    const uint32_t* __restrict__ order,
    int* __restrict__ out)
{
    const int i = blockIdx.x * 256 + threadIdx.x;
    if (i < N_BOX) {
        bool sup = (remv[i >> 6] >> (i & 63)) & 1ull;
        out[order[i]] = sup ? 0 : 1;
    }
}

extern "C" void kernel_launch(void* const* d_in, const int* in_sizes, int n_in,
                              void* d_out, int out_size, void* d_ws, size_t ws_size,
                              hipStream_t stream) {
    const float* boxes  = (const float*)d_in[0];
    const float* scores = (const float*)d_in[1];
    int* out = (int*)d_out;
    char* ws = (char*)d_ws;

    // ws layout (8-byte aligned chunks)
    unsigned long long* mask = (unsigned long long*)ws;            // 8 MB
    char* p = ws + (size_t)N_BOX * NWORDS * sizeof(unsigned long long);
    uint32_t* order = (uint32_t*)p;            p += N_BOX * 4;
    float* sx1   = (float*)p;                  p += N_BOX * 4;
    float* sy1   = (float*)p;                  p += N_BOX * 4;
    float* sx2   = (float*)p;                  p += N_BOX * 4;
    float* sy2   = (float*)p;                  p += N_BOX * 4;
    float* sarea = (float*)p;                  p += N_BOX * 4;
    unsigned long long* remv = (unsigned long long*)p;

    hipLaunchKernelGGL(sort_kernel, dim3(1), dim3(1024),
                       N_BOX * sizeof(unsigned long long), stream,
                       boxes, scores, order, sx1, sy1, sx2, sy2, sarea);

    mask_kernel<<<dim3(NWORDS, NWORDS), 64, 0, stream>>>(
        sx1, sy1, sx2, sy2, sarea, mask);

    scan_kernel<<<1, 1024, 0, stream>>>(mask, remv);

    output_kernel<<<(N_BOX + 255) / 256, 256, 0, stream>>>(remv, order, out);
}

// Round 9
// 600.153 us; speedup vs baseline: 1.3086x; 1.3086x over previous
//
#include <hip/hip_runtime.h>
#include <stdint.h>

#define N_BOX 8192
#define NWORDS 128   // N_BOX / 64

// ---------------------------------------------------------------------------
// Kernel 1: stable descending sort by score via bitonic sort of uint64 keys.
// key = (score_bits << 32) | (0xFFFFFFFF - idx)  -> descending sort gives
// score desc, ties broken by original index ascending (matches stable
// jnp.argsort(-scores)). Scores are >= 0 so raw float bits are monotonic.
// Then gather sorted boxes + areas.
// ---------------------------------------------------------------------------
__global__ __launch_bounds__(1024) void sort_kernel(
    const float* __restrict__ boxes, const float* __restrict__ scores,
    uint32_t* __restrict__ order,
    float* __restrict__ sx1, float* __restrict__ sy1,
    float* __restrict__ sx2, float* __restrict__ sy2,
    float* __restrict__ sarea)
{
    extern __shared__ unsigned long long s[];
    const int tid = threadIdx.x;

    for (int i = tid; i < N_BOX; i += 1024) {
        uint32_t bits = __float_as_uint(scores[i]);
        s[i] = ((unsigned long long)bits << 32) |
               (unsigned long long)(0xFFFFFFFFu - (uint32_t)i);
    }
    __syncthreads();

    for (int k = 2; k <= N_BOX; k <<= 1) {
        for (int j = k >> 1; j > 0; j >>= 1) {
            for (int idx = tid; idx < N_BOX; idx += 1024) {
                int ixj = idx ^ j;
                if (ixj > idx) {
                    unsigned long long a = s[idx], b = s[ixj];
                    bool desc = ((idx & k) == 0);   // final pass: all descending
                    if (desc ? (a < b) : (a > b)) { s[idx] = b; s[ixj] = a; }
                }
            }
            __syncthreads();
        }
    }

    for (int i = tid; i < N_BOX; i += 1024) {
        unsigned long long key = s[i];
        uint32_t idx = 0xFFFFFFFFu - (uint32_t)(key & 0xFFFFFFFFull);
        order[i] = idx;
        float x1 = boxes[idx * 4 + 0], y1 = boxes[idx * 4 + 1];
        float x2 = boxes[idx * 4 + 2], y2 = boxes[idx * 4 + 3];
        sx1[i] = x1; sy1[i] = y1; sx2[i] = x2; sy2[i] = y2;
        sarea[i] = (x2 - x1 + 1.0f) * (y2 - y1 + 1.0f);
    }
}

// ---------------------------------------------------------------------------
// Kernel 2: suppression bitmask. Block = 64 threads = 64 rows; each block
// handles one (row_block, col_block) 64x64 tile, col_block >= row_block.
// Bit c of mask[i][cb] set iff iou(i, cb*64+c) > 0.5 and j > i.
// Float op order matches the reference exactly: (a_i + a_j) - inter, true
// division. An empty asm barrier pins the ROUNDED value of `inter` so
// -ffp-contract=fast (hipcc default) cannot fuse `ssum - w*h` into an fma,
// which would skip numpy's intermediate rounding and could flip iou>0.5
// at the boundary.
// ---------------------------------------------------------------------------
__global__ __launch_bounds__(64) void mask_kernel(
    const float* __restrict__ sx1, const float* __restrict__ sy1,
    const float* __restrict__ sx2, const float* __restrict__ sy2,
    const float* __restrict__ sarea,
    unsigned long long* __restrict__ mask)
{
    const int cb = blockIdx.x, rb = blockIdx.y;
    if (cb < rb) return;

    __shared__ float cx1[64], cy1[64], cx2[64], cy2[64], ca[64];
    const int l = threadIdx.x;
    const int j0 = cb * 64;
    cx1[l] = sx1[j0 + l]; cy1[l] = sy1[j0 + l];
    cx2[l] = sx2[j0 + l]; cy2[l] = sy2[j0 + l];
    ca[l]  = sarea[j0 + l];
    __syncthreads();

    const int i = rb * 64 + l;
    const float x1 = sx1[i], y1 = sy1[i], x2 = sx2[i], y2 = sy2[i];
    const float ai = sarea[i];

    unsigned long long m = 0ull;
    for (int c = 0; c < 64; ++c) {
        const int j = j0 + c;
        float xx1 = fmaxf(x1, cx1[c]);
        float yy1 = fmaxf(y1, cy1[c]);
        float xx2 = fminf(x2, cx2[c]);
        float yy2 = fminf(y2, cy2[c]);
        float w = fmaxf(xx2 - xx1 + 1.0f, 0.0f);
        float h = fmaxf(yy2 - yy1 + 1.0f, 0.0f);
        float inter = w * h;
        asm volatile("" : "+v"(inter));   // pin rounded mul; block fma contraction
        float ssum  = ai + ca[c];
        float denom = ssum - inter;
        float iou   = inter / denom;
        if ((iou > 0.5f) && (j > i)) m |= (1ull << c);
    }
    mask[(size_t)i * NWORDS + cb] = m;
}

// ---------------------------------------------------------------------------
// Kernel 3 (REWRITTEN): latency-optimized sequential greedy scan.
// Single block, 1024 threads. Per chunk b (64 boxes):
//   A. prefetch chunk b+1's 64 diagonal words into registers (hidden)
//   B. issue ALL OR-phase row-words unconditionally (8 per thread, in
//      flight during the scan; columns t<=b skipped as dead)
//   C. every thread redundantly runs the 64-step greedy recurrence from
//      the LDS diagonal buffer (uniform broadcast reads, fully unrolled,
//      branchless, register-resident) -> rem/kept identical everywhere;
//      no shfl, no cross-lane traffic.  Safe vs tid0's concurrent
//      finalize-write because diagonal words only carry bits > their row
//      (j>i in mask_kernel) -> the recurrence is idempotent.
//   D. branchless kept-masked OR of the preloaded words -> ds atomicOr
//   E. ds_write the prefetched diagonal into the other buffer
//   F. one barrier
// ---------------------------------------------------------------------------
__global__ __launch_bounds__(1024) void scan_kernel(
    const unsigned long long* __restrict__ mask,
    unsigned long long* __restrict__ remv_out)
{
    __shared__ unsigned long long diag[2][64];   // double-buffered diagonal
    __shared__ unsigned long long remv[NWORDS];  // suppression state per word
    const int tid = threadIdx.x;
    const int t = tid & 127;      // column word this thread owns
    const int g = tid >> 7;       // row group 0..7 (8 rows each)

    if (tid < NWORDS) remv[tid] = 0ull;
    if (tid < 64) diag[0][tid] = mask[(size_t)tid * NWORDS + 0];
    __syncthreads();

    for (int b = 0; b < NWORDS; ++b) {
        const int cur = b & 1;

        // A. prefetch next chunk's diagonal (latency hidden under C)
        unsigned long long dnext = 0ull;
        if (b + 1 < NWORDS && tid < 64)
            dnext = mask[(size_t)((b + 1) * 64 + tid) * NWORDS + (b + 1)];

        // B. issue OR-phase loads up front, unconditional w.r.t. kept
        unsigned long long ld[8];
        if (t > b) {
            #pragma unroll
            for (int i = 0; i < 8; ++i)
                ld[i] = mask[(size_t)(b * 64 + g * 8 + i) * NWORDS + t];
        }

        // C. serial greedy recurrence, replicated in every thread
        unsigned long long rem = remv[b];
        unsigned long long dbuf[8], dnbuf[8];
        #pragma unroll
        for (int i = 0; i < 8; ++i) dbuf[i] = diag[cur][i];
        #pragma unroll
        for (int gg = 0; gg < 8; ++gg) {
            if (gg < 7) {
                #pragma unroll
                for (int i = 0; i < 8; ++i)
                    dnbuf[i] = diag[cur][gg * 8 + 8 + i];
            }
            #pragma unroll
            for (int i = 0; i < 8; ++i) {
                const int bit = gg * 8 + i;
                // suppressed bit set -> msk = 0; clear -> msk = all-ones
                unsigned long long msk = ((rem >> bit) & 1ull) - 1ull;
                rem |= dbuf[i] & msk;
            }
            #pragma unroll
            for (int i = 0; i < 8; ++i) dbuf[i] = dnbuf[i];
        }
        const unsigned long long kept = ~rem;
        if (tid == 0) remv[b] = rem;   // finalize own chunk's state

        // D. branchless kept-masked combine, one LDS atomic per thread
        if (t > b) {
            unsigned long long acc = 0ull;
            #pragma unroll
            for (int i = 0; i < 8; ++i) {
                unsigned long long km = (kept >> (g * 8 + i)) & 1ull;
                acc |= ld[i] & (0ull - km);
            }
            if (acc) atomicOr(&remv[t], acc);
        }

        // E. land the diagonal prefetch
        if (b + 1 < NWORDS && tid < 64) diag[cur ^ 1][tid] = dnext;

        // F. single barrier per chunk
        __syncthreads();
    }

    if (tid < NWORDS) remv_out[tid] = remv[tid];
}

// ---------------------------------------------------------------------------
// Kernel 4: scatter keep mask back to original order as int32 0/1.
// The reference output dtype is bool -> harness reads d_out as int32.
// ---------------------------------------------------------------------------
__global__ __launch_bounds__(256) void output_kernel(
    const unsigned long long* __restrict__ remv,
    const uint32_t* __restrict__ order,
    int* __restrict__ out)
{
    const int i = blockIdx.x * 256 + threadIdx.x;
    if (i < N_BOX) {
        bool sup = (remv[i >> 6] >> (i & 63)) & 1ull;
        out[order[i]] = sup ? 0 : 1;
    }
}

extern "C" void kernel_launch(void* const* d_in, const int* in_sizes, int n_in,
                              void* d_out, int out_size, void* d_ws, size_t ws_size,
                              hipStream_t stream) {
    const float* boxes  = (const float*)d_in[0];
    const float* scores = (const float*)d_in[1];
    int* out = (int*)d_out;
    char* ws = (char*)d_ws;

    // ws layout (8-byte aligned chunks)
    unsigned long long* mask = (unsigned long long*)ws;            // 8 MB
    char* p = ws + (size_t)N_BOX * NWORDS * sizeof(unsigned long long);
    uint32_t* order = (uint32_t*)p;            p += N_BOX * 4;
    float* sx1   = (float*)p;                  p += N_BOX * 4;
    float* sy1   = (float*)p;                  p += N_BOX * 4;
    float* sx2   = (float*)p;                  p += N_BOX * 4;
    float* sy2   = (float*)p;                  p += N_BOX * 4;
    float* sarea = (float*)p;                  p += N_BOX * 4;
    unsigned long long* remv = (unsigned long long*)p;

    hipLaunchKernelGGL(sort_kernel, dim3(1), dim3(1024),
                       N_BOX * sizeof(unsigned long long), stream,
                       boxes, scores, order, sx1, sy1, sx2, sy2, sarea);

    mask_kernel<<<dim3(NWORDS, NWORDS), 64, 0, stream>>>(
        sx1, sy1, sx2, sy2, sarea, mask);

    scan_kernel<<<1, 1024, 0, stream>>>(mask, remv);

    output_kernel<<<(N_BOX + 255) / 256, 256, 0, stream>>>(remv, order, out);
}

// Round 10
// 478.024 us; speedup vs baseline: 1.6429x; 1.2555x over previous
//
#include <hip/hip_runtime.h>
#include <stdint.h>

#define N_BOX 8192
#define NWORDS 128   // N_BOX / 64

// ---------------------------------------------------------------------------
// Kernel 1: stable descending sort by score via bitonic sort of uint64 keys.
// key = (score_bits << 32) | (0xFFFFFFFF - idx)  -> descending sort gives
// score desc, ties broken by original index ascending (matches stable
// jnp.argsort(-scores)). Scores are >= 0 so raw float bits are monotonic.
// Then gather sorted boxes + areas.
// ---------------------------------------------------------------------------
__global__ __launch_bounds__(1024) void sort_kernel(
    const float* __restrict__ boxes, const float* __restrict__ scores,
    uint32_t* __restrict__ order,
    float* __restrict__ sx1, float* __restrict__ sy1,
    float* __restrict__ sx2, float* __restrict__ sy2,
    float* __restrict__ sarea)
{
    extern __shared__ unsigned long long s[];
    const int tid = threadIdx.x;

    for (int i = tid; i < N_BOX; i += 1024) {
        uint32_t bits = __float_as_uint(scores[i]);
        s[i] = ((unsigned long long)bits << 32) |
               (unsigned long long)(0xFFFFFFFFu - (uint32_t)i);
    }
    __syncthreads();

    for (int k = 2; k <= N_BOX; k <<= 1) {
        for (int j = k >> 1; j > 0; j >>= 1) {
            for (int idx = tid; idx < N_BOX; idx += 1024) {
                int ixj = idx ^ j;
                if (ixj > idx) {
                    unsigned long long a = s[idx], b = s[ixj];
                    bool desc = ((idx & k) == 0);   // final pass: all descending
                    if (desc ? (a < b) : (a > b)) { s[idx] = b; s[ixj] = a; }
                }
            }
            __syncthreads();
        }
    }

    for (int i = tid; i < N_BOX; i += 1024) {
        unsigned long long key = s[i];
        uint32_t idx = 0xFFFFFFFFu - (uint32_t)(key & 0xFFFFFFFFull);
        order[i] = idx;
        float x1 = boxes[idx * 4 + 0], y1 = boxes[idx * 4 + 1];
        float x2 = boxes[idx * 4 + 2], y2 = boxes[idx * 4 + 3];
        sx1[i] = x1; sy1[i] = y1; sx2[i] = x2; sy2[i] = y2;
        sarea[i] = (x2 - x1 + 1.0f) * (y2 - y1 + 1.0f);
    }
}

// ---------------------------------------------------------------------------
// Kernel 2: suppression bitmask. Block = 64 threads = 64 rows; each block
// handles one (row_block, col_block) 64x64 tile, col_block >= row_block.
// Bit c of mask[i][cb] set iff iou(i, cb*64+c) > 0.5 and j > i.
// Float op order matches the reference exactly: (a_i + a_j) - inter, true
// division. An empty asm barrier pins the ROUNDED value of `inter` so
// -ffp-contract=fast (hipcc default) cannot fuse `ssum - w*h` into an fma,
// which would skip numpy's intermediate rounding and could flip iou>0.5
// at the boundary.
// ---------------------------------------------------------------------------
__global__ __launch_bounds__(64) void mask_kernel(
    const float* __restrict__ sx1, const float* __restrict__ sy1,
    const float* __restrict__ sx2, const float* __restrict__ sy2,
    const float* __restrict__ sarea,
    unsigned long long* __restrict__ mask)
{
    const int cb = blockIdx.x, rb = blockIdx.y;
    if (cb < rb) return;

    __shared__ float cx1[64], cy1[64], cx2[64], cy2[64], ca[64];
    const int l = threadIdx.x;
    const int j0 = cb * 64;
    cx1[l] = sx1[j0 + l]; cy1[l] = sy1[j0 + l];
    cx2[l] = sx2[j0 + l]; cy2[l] = sy2[j0 + l];
    ca[l]  = sarea[j0 + l];
    __syncthreads();

    const int i = rb * 64 + l;
    const float x1 = sx1[i], y1 = sy1[i], x2 = sx2[i], y2 = sy2[i];
    const float ai = sarea[i];

    unsigned long long m = 0ull;
    for (int c = 0; c < 64; ++c) {
        const int j = j0 + c;
        float xx1 = fmaxf(x1, cx1[c]);
        float yy1 = fmaxf(y1, cy1[c]);
        float xx2 = fminf(x2, cx2[c]);
        float yy2 = fminf(y2, cy2[c]);
        float w = fmaxf(xx2 - xx1 + 1.0f, 0.0f);
        float h = fmaxf(yy2 - yy1 + 1.0f, 0.0f);
        float inter = w * h;
        asm volatile("" : "+v"(inter));   // pin rounded mul; block fma contraction
        float ssum  = ai + ca[c];
        float denom = ssum - inter;
        float iou   = inter / denom;
        if ((iou > 0.5f) && (j > i)) m |= (1ull << c);
    }
    mask[(size_t)i * NWORDS + cb] = m;
}

// ---------------------------------------------------------------------------
// Kernel 3 (v3): single-wave serial scan + parallel OR-phase.
// Round-9 post-mortem: replicating the 64-step scan in all 16 waves
// saturated the LDS pipe (16 x 64 broadcast ds_read_b64 per iteration)
// and multiplied VALU issue 16x -> 2.85us/iter. Now only wave 0 runs the
// chain (1x LDS + 1x VALU); kept is published via LDS and a second
// barrier separates publish from consume.
// Per chunk b:
//   B. all threads: issue OR-phase row-word loads (latency hidden by scan)
//   C. wave0: prefetch next diagonal (global), run 64-step greedy chain
//      from diag LDS (broadcast reads, pipelined), publish rem/kept
//   barrier1
//   D. all threads: branchless kept-masked OR -> LDS atomicOr on remv
//   barrier2 (remv settled before next iteration reads remv[b+1])
// ---------------------------------------------------------------------------
__global__ __launch_bounds__(1024) void scan_kernel(
    const unsigned long long* __restrict__ mask,
    unsigned long long* __restrict__ remv_out)
{
    __shared__ unsigned long long diag[2][64];   // double-buffered diagonal
    __shared__ unsigned long long remv[NWORDS];  // suppression state per word
    __shared__ unsigned long long keptS;
    const int tid = threadIdx.x;
    const int t = tid & 127;      // column word this thread owns
    const int g = tid >> 7;       // row group 0..7 (8 rows each)

    if (tid < NWORDS) remv[tid] = 0ull;
    if (tid < 64) diag[0][tid] = mask[(size_t)tid * NWORDS + 0];
    __syncthreads();

    for (int b = 0; b < NWORDS; ++b) {
        const int cur = b & 1;

        // B. issue OR-phase loads up front (all threads; in flight during C)
        unsigned long long ld[8];
        if (t > b) {
            #pragma unroll
            for (int i = 0; i < 8; ++i)
                ld[i] = mask[(size_t)(b * 64 + g * 8 + i) * NWORDS + t];
        }

        // C. wave0-only: next-diag prefetch + serial greedy recurrence
        if (tid < 64) {
            unsigned long long dnext = 0ull;
            if (b + 1 < NWORDS)
                dnext = mask[(size_t)((b + 1) * 64 + tid) * NWORDS + (b + 1)];

            unsigned long long rem = remv[b];
            #pragma unroll
            for (int i = 0; i < 64; ++i) {
                unsigned long long di = diag[cur][i];   // uniform broadcast
                // bit i set -> msk = 0; clear -> msk = all-ones
                unsigned long long msk = ((rem >> i) & 1ull) - 1ull;
                rem |= di & msk;
            }
            if (tid == 0) { remv[b] = rem; keptS = ~rem; }
            if (b + 1 < NWORDS) diag[cur ^ 1][tid] = dnext;
        }
        __syncthreads();   // barrier 1: keptS visible to all

        // D. branchless kept-masked combine, one LDS atomic per thread
        const unsigned long long kept = keptS;
        if (t > b) {
            unsigned long long acc = 0ull;
            #pragma unroll
            for (int i = 0; i < 8; ++i) {
                unsigned long long km = (kept >> (g * 8 + i)) & 1ull;
                acc |= ld[i] & (0ull - km);
            }
            if (acc) atomicOr(&remv[t], acc);
        }
        __syncthreads();   // barrier 2: remv settled for next iteration
    }

    if (tid < NWORDS) remv_out[tid] = remv[tid];
}

// ---------------------------------------------------------------------------
// Kernel 4: scatter keep mask back to original order as int32 0/1.
// The reference output dtype is bool -> harness reads d_out as int32.
// ---------------------------------------------------------------------------
__global__ __launch_bounds__(256) void output_kernel(
    const unsigned long long* __restrict__ remv,
    const uint32_t* __restrict__ order,
    int* __restrict__ out)
{
    const int i = blockIdx.x * 256 + threadIdx.x;
    if (i < N_BOX) {
        bool sup = (remv[i >> 6] >> (i & 63)) & 1ull;
        out[order[i]] = sup ? 0 : 1;
    }
}

extern "C" void kernel_launch(void* const* d_in, const int* in_sizes, int n_in,
                              void* d_out, int out_size, void* d_ws, size_t ws_size,
                              hipStream_t stream) {
    const float* boxes  = (const float*)d_in[0];
    const float* scores = (const float*)d_in[1];
    int* out = (int*)d_out;
    char* ws = (char*)d_ws;

    // ws layout (8-byte aligned chunks)
    unsigned long long* mask = (unsigned long long*)ws;            // 8 MB
    char* p = ws + (size_t)N_BOX * NWORDS * sizeof(unsigned long long);
    uint32_t* order = (uint32_t*)p;            p += N_BOX * 4;
    float* sx1   = (float*)p;                  p += N_BOX * 4;
    float* sy1   = (float*)p;                  p += N_BOX * 4;
    float* sx2   = (float*)p;                  p += N_BOX * 4;
    float* sy2   = (float*)p;                  p += N_BOX * 4;
    float* sarea = (float*)p;                  p += N_BOX * 4;
    unsigned long long* remv = (unsigned long long*)p;

    hipLaunchKernelGGL(sort_kernel, dim3(1), dim3(1024),
                       N_BOX * sizeof(unsigned long long), stream,
                       boxes, scores, order, sx1, sy1, sx2, sy2, sarea);

    mask_kernel<<<dim3(NWORDS, NWORDS), 64, 0, stream>>>(
        sx1, sy1, sx2, sy2, sarea, mask);

    scan_kernel<<<1, 1024, 0, stream>>>(mask, remv);

    output_kernel<<<(N_BOX + 255) / 256, 256, 0, stream>>>(remv, order, out);
}

// Round 15
// 477.378 us; speedup vs baseline: 1.6452x; 1.0014x over previous
//
#include <hip/hip_runtime.h>
#include <stdint.h>

#define N_BOX 8192
#define NWORDS 128   // N_BOX / 64

// ---------------------------------------------------------------------------
// Kernel 1: stable descending sort by score via bitonic sort of uint64 keys.
// key = (score_bits << 32) | (0xFFFFFFFF - idx)  -> descending sort gives
// score desc, ties broken by original index ascending (matches stable
// jnp.argsort(-scores)). Scores are >= 0 so raw float bits are monotonic.
// Then gather sorted boxes + areas.
// ---------------------------------------------------------------------------
__global__ __launch_bounds__(1024) void sort_kernel(
    const float* __restrict__ boxes, const float* __restrict__ scores,
    uint32_t* __restrict__ order,
    float* __restrict__ sx1, float* __restrict__ sy1,
    float* __restrict__ sx2, float* __restrict__ sy2,
    float* __restrict__ sarea)
{
    extern __shared__ unsigned long long s[];
    const int tid = threadIdx.x;

    for (int i = tid; i < N_BOX; i += 1024) {
        uint32_t bits = __float_as_uint(scores[i]);
        s[i] = ((unsigned long long)bits << 32) |
               (unsigned long long)(0xFFFFFFFFu - (uint32_t)i);
    }
    __syncthreads();

    for (int k = 2; k <= N_BOX; k <<= 1) {
        for (int j = k >> 1; j > 0; j >>= 1) {
            for (int idx = tid; idx < N_BOX; idx += 1024) {
                int ixj = idx ^ j;
                if (ixj > idx) {
                    unsigned long long a = s[idx], b = s[ixj];
                    bool desc = ((idx & k) == 0);   // final pass: all descending
                    if (desc ? (a < b) : (a > b)) { s[idx] = b; s[ixj] = a; }
                }
            }
            __syncthreads();
        }
    }

    for (int i = tid; i < N_BOX; i += 1024) {
        unsigned long long key = s[i];
        uint32_t idx = 0xFFFFFFFFu - (uint32_t)(key & 0xFFFFFFFFull);
        order[i] = idx;
        float x1 = boxes[idx * 4 + 0], y1 = boxes[idx * 4 + 1];
        float x2 = boxes[idx * 4 + 2], y2 = boxes[idx * 4 + 3];
        sx1[i] = x1; sy1[i] = y1; sx2[i] = x2; sy2[i] = y2;
        sarea[i] = (x2 - x1 + 1.0f) * (y2 - y1 + 1.0f);
    }
}

// ---------------------------------------------------------------------------
// Kernel 2: suppression bitmask. Block = 64 threads = 64 rows; each block
// handles one (row_block, col_block) 64x64 tile, col_block >= row_block.
// Bit c of mask[i][cb] set iff iou(i, cb*64+c) > 0.5 and j > i.
// Float op order matches the reference exactly: (a_i + a_j) - inter, true
// division. An empty asm barrier pins the ROUNDED value of `inter` so
// -ffp-contract=fast (hipcc default) cannot fuse `ssum - w*h` into an fma,
// which would skip numpy's intermediate rounding and could flip iou>0.5
// at the boundary.
// ---------------------------------------------------------------------------
__global__ __launch_bounds__(64) void mask_kernel(
    const float* __restrict__ sx1, const float* __restrict__ sy1,
    const float* __restrict__ sx2, const float* __restrict__ sy2,
    const float* __restrict__ sarea,
    unsigned long long* __restrict__ mask)
{
    const int cb = blockIdx.x, rb = blockIdx.y;
    if (cb < rb) return;

    __shared__ float cx1[64], cy1[64], cx2[64], cy2[64], ca[64];
    const int l = threadIdx.x;
    const int j0 = cb * 64;
    cx1[l] = sx1[j0 + l]; cy1[l] = sy1[j0 + l];
    cx2[l] = sx2[j0 + l]; cy2[l] = sy2[j0 + l];
    ca[l]  = sarea[j0 + l];
    __syncthreads();

    const int i = rb * 64 + l;
    const float x1 = sx1[i], y1 = sy1[i], x2 = sx2[i], y2 = sy2[i];
    const float ai = sarea[i];

    unsigned long long m = 0ull;
    for (int c = 0; c < 64; ++c) {
        const int j = j0 + c;
        float xx1 = fmaxf(x1, cx1[c]);
        float yy1 = fmaxf(y1, cy1[c]);
        float xx2 = fminf(x2, cx2[c]);
        float yy2 = fminf(y2, cy2[c]);
        float w = fmaxf(xx2 - xx1 + 1.0f, 0.0f);
        float h = fmaxf(yy2 - yy1 + 1.0f, 0.0f);
        float inter = w * h;
        asm volatile("" : "+v"(inter));   // pin rounded mul; block fma contraction
        float ssum  = ai + ca[c];
        float denom = ssum - inter;
        float iou   = inter / denom;
        if ((iou > 0.5f) && (j > i)) m |= (1ull << c);
    }
    mask[(size_t)i * NWORDS + cb] = m;
}

// ---------------------------------------------------------------------------
// Kernel 3 (v4): single-wave scan + asm-staged OR-phase loads.
// R10 post-mortem: VGPR=36 proved the compiler sank the OR-phase loads to
// phase D (exposed ~500cy/iter), and the un-staged diag reads exposed LDS
// latency in the chain. Fixes:
//  - B: loads issued via inline-asm global_load_dwordx2 (compiler cannot
//    sink them); consumed in D after explicit s_waitcnt vmcnt(0) +
//    sched_barrier(0)  [rule #18: asm wait needs the sched fence].
//    Latency hidden under the entire C chain.
//  - C: wave0 chain with 8-ahead dbuf/dnbuf register staging of diag
//    (issue next 8 ds_reads before consuming current 8).
// ---------------------------------------------------------------------------
__global__ __launch_bounds__(1024) void scan_kernel(
    const unsigned long long* __restrict__ mask,
    unsigned long long* __restrict__ remv_out)
{
    __shared__ unsigned long long diag[2][64];   // double-buffered diagonal
    __shared__ unsigned long long remv[NWORDS];  // suppression state per word
    __shared__ unsigned long long keptS;
    const int tid = threadIdx.x;
    const int t = tid & 127;      // column word this thread owns
    const int g = tid >> 7;       // row group 0..7 (8 rows each)

    if (tid < NWORDS) remv[tid] = 0ull;
    if (tid < 64) diag[0][tid] = mask[(size_t)tid * NWORDS + 0];
    __syncthreads();

    for (int b = 0; b < NWORDS; ++b) {
        const int cur = b & 1;

        // B. issue OR-phase loads via raw asm (issue only, no wait here;
        //    in flight across the whole C phase)
        unsigned long long ld[8];
        if (t > b) {
            const unsigned long long* base =
                &mask[(size_t)(b * 64 + g * 8) * NWORDS + t];
            #pragma unroll
            for (int i = 0; i < 8; ++i) {
                const unsigned long long* ap = base + (size_t)i * NWORDS;
                asm volatile("global_load_dwordx2 %0, %1, off"
                             : "=v"(ld[i]) : "v"(ap));
            }
        }

        // C. wave0-only: next-diag prefetch + serial greedy recurrence with
        //    8-ahead register staging of the diagonal words
        if (tid < 64) {
            unsigned long long dnext = 0ull;
            if (b + 1 < NWORDS)
                dnext = mask[(size_t)((b + 1) * 64 + tid) * NWORDS + (b + 1)];

            unsigned long long rem = remv[b];
            unsigned long long dbuf[8], dnbuf[8];
            #pragma unroll
            for (int i = 0; i < 8; ++i) dbuf[i] = diag[cur][i];
            #pragma unroll
            for (int gg = 0; gg < 8; ++gg) {
                if (gg < 7) {
                    #pragma unroll
                    for (int i = 0; i < 8; ++i)
                        dnbuf[i] = diag[cur][gg * 8 + 8 + i];
                }
                #pragma unroll
                for (int i = 0; i < 8; ++i) {
                    const int bit = gg * 8 + i;
                    // bit set -> msk = 0; clear -> msk = all-ones
                    unsigned long long msk = ((rem >> bit) & 1ull) - 1ull;
                    rem |= dbuf[i] & msk;
                }
                #pragma unroll
                for (int i = 0; i < 8; ++i) dbuf[i] = dnbuf[i];
            }
            if (tid == 0) { remv[b] = rem; keptS = ~rem; }
            if (b + 1 < NWORDS) diag[cur ^ 1][tid] = dnext;
        }
        __syncthreads();   // barrier 1: keptS visible (also drains vmcnt)

        // D. ensure asm loads landed, then branchless kept-masked combine
        asm volatile("s_waitcnt vmcnt(0)" ::: "memory");
        __builtin_amdgcn_sched_barrier(0);
        const unsigned long long kept = keptS;
        if (t > b) {
            unsigned long long acc = 0ull;
            #pragma unroll
            for (int i = 0; i < 8; ++i) {
                unsigned long long km = (kept >> (g * 8 + i)) & 1ull;
                acc |= ld[i] & (0ull - km);
            }
            if (acc) atomicOr(&remv[t], acc);
        }
        __syncthreads();   // barrier 2: remv settled for next iteration
    }

    if (tid < NWORDS) remv_out[tid] = remv[tid];
}

// ---------------------------------------------------------------------------
// Kernel 4: scatter keep mask back to original order as int32 0/1.
// The reference output dtype is bool -> harness reads d_out as int32.
// ---------------------------------------------------------------------------
__global__ __launch_bounds__(256) void output_kernel(
    const unsigned long long* __restrict__ remv,
    const uint32_t* __restrict__ order,
    int* __restrict__ out)
{
    const int i = blockIdx.x * 256 + threadIdx.x;
    if (i < N_BOX) {
        bool sup = (remv[i >> 6] >> (i & 63)) & 1ull;
        out[order[i]] = sup ? 0 : 1;
    }
}

extern "C" void kernel_launch(void* const* d_in, const int* in_sizes, int n_in,
                              void* d_out, int out_size, void* d_ws, size_t ws_size,
                              hipStream_t stream) {
    const float* boxes  = (const float*)d_in[0];
    const float* scores = (const float*)d_in[1];
    int* out = (int*)d_out;
    char* ws = (char*)d_ws;

    // ws layout (8-byte aligned chunks)
    unsigned long long* mask = (unsigned long long*)ws;            // 8 MB
    char* p = ws + (size_t)N_BOX * NWORDS * sizeof(unsigned long long);
    uint32_t* order = (uint32_t*)p;            p += N_BOX * 4;
    float* sx1   = (float*)p;                  p += N_BOX * 4;
    float* sy1   = (float*)p;                  p += N_BOX * 4;
    float* sx2   = (float*)p;                  p += N_BOX * 4;
    float* sy2   = (float*)p;                  p += N_BOX * 4;
    float* sarea = (float*)p;                  p += N_BOX * 4;
    unsigned long long* remv = (unsigned long long*)p;

    hipLaunchKernelGGL(sort_kernel, dim3(1), dim3(1024),
                       N_BOX * sizeof(unsigned long long), stream,
                       boxes, scores, order, sx1, sy1, sx2, sy2, sarea);

    mask_kernel<<<dim3(NWORDS, NWORDS), 64, 0, stream>>>(
        sx1, sy1, sx2, sy2, sarea, mask);

    scan_kernel<<<1, 1024, 0, stream>>>(mask, remv);

    output_kernel<<<(N_BOX + 255) / 256, 256, 0, stream>>>(remv, order, out);
}